// Round 1
// baseline (357.134 us; speedup 1.0000x reference)
//
#include <hip/hip_runtime.h>
#include <cstdint>
#include <cstddef>

// Binarized basic block on MI355X.
// |acc| <= 9*128 = 1152 < THRESH=8000 -> the per-partial-sum clip never binds
// -> both convs are exact int convolutions of sign() values. int8 implicit
// GEMM via mfma_i32_16x16x64_i8; float ops bit-exact vs numpy fp32.
//
// R10 (on R9 base): O-SPLIT FOR OCCUPANCY.
//  R9 counters: MfmaUtil 10.9, VALUBusy 7.7, HBM 26%, Occ 18% -> all pipes
//  idle = latency-bound at 8 waves/CU (LDS 147 KB -> 1 block/CU). Per K-step
//  the CU drains 64 ds_read_b128 (~768 cyc) but each wave only has ~650 cyc
//  of MFMA slack and only 1 other wave/SIMD to hide behind.
//  -> Split 128 O into two 64-O blocks along nsub (B-frag n axis): LDS/block
//     73,728 B -> 2 blocks/CU -> 16 waves/CU (4/SIMD). Same per-CU MFMA and
//     LDS traffic, ~90 VGPR (<=128 enforced by __launch_bounds__(512,4)).
//  -> O-half pairs are 8 bids apart => same XCD: shared xs reads and the
//     4-B interleaved phase-1 stores merge in one L2.
//  -> Tail: 196 tasks/XCD = 3*64 + 4; leftovers run as 8 RG=1 half-tasks on
//     blocks local<8 -> wall 3.5 rounds (as R9).

typedef int      v4i __attribute__((ext_vector_type(4)));
typedef float    v4f __attribute__((ext_vector_type(4)));

constexpr int B = 64, C = 128, H = 56, W = 56;
constexpr int HP = H + 2, WP = W + 2;      // zero-padded spatial
constexpr int PIX = H * W;                 // 3136
constexpr int M = B * H * W;               // 200704 = 784 * 256
constexpr int NTILES = M / 256;            // 784 tiles of 256 rows
constexpr int TPX = NTILES / 8;            // 98 tiles per XCD

// workspace layout (bytes)
constexpr size_t XS_BYTES = (size_t)B * HP * WP * C;   // 27,557,888
constexpr size_t XS1_OFF = 0;
constexpr size_t XS2_OFF = XS_BYTES;
constexpr size_t WF_BYTES = 18 * 8192;                 // 147,456
constexpr size_t WF1_OFF = 2 * XS_BYTES;
constexpr size_t WF2_OFF = WF1_OFF + WF_BYTES;
constexpr size_t BNP_OFF = WF2_OFF + WF_BYTES;         // 4*128 floats

// step = r*6 + kh*3 + s  (r = step/6, kh = (step/3)&1, s = step%3)
// s-adjacent steps are distance-1 in x -> L1-resident window (R9).
__device__ __forceinline__ int step_aoff(int st) {
    int r = st / 6, kh = (st / 3) & 1, s = st % 3;
    return (r * WP + s) * C + kh * 64;
}

// ---------------------------------------------------------------------------
// Zero only the padded halos of xs1/xs2. 256 blocks: 4 per image.
__global__ __launch_bounds__(256) void zero_halo(int8_t* __restrict__ xs1,
                                                 int8_t* __restrict__ xs2) {
    int b = blockIdx.x >> 2;
    int q = blockIdx.x & 3;
    int t = q * 256 + threadIdx.x;           // 0..1023
    size_t ib = (size_t)b * HP * WP * C;
#pragma unroll
    for (int a = 0; a < 2; ++a) {
        uint32_t* p = (uint32_t*)((a ? xs2 : xs1) + ib);
        const int ROWD = WP * C / 4;             // 1856 dwords per padded row
        for (int i = t; i < ROWD; i += 1024) {
            p[i] = 0;
            p[(HP - 1) * ROWD + i] = 0;
        }
        for (int i = t; i < 56 * 2 * 32; i += 1024) {
            int r = i >> 6;
            int side = (i >> 5) & 1;
            int j = i & 31;
            p[((r + 1) * WP + side * (WP - 1)) * (C / 4) + j] = 0;
        }
    }
}

// ---------------------------------------------------------------------------
// sign(x) -> padded NHWC int8 via LDS transpose (16 B/lane full-line stores).
__global__ __launch_bounds__(256) void prep_x(const float* __restrict__ x,
                                              int8_t* __restrict__ xs) {
    __shared__ uint32_t tl[256 * 33];
    int t = threadIdx.x;
    int m = blockIdx.x * 256 + t;
    int b_ = m / PIX, hw = m % PIX;
    const float* xp = x + (size_t)b_ * C * PIX + hw;
#pragma unroll
    for (int c4 = 0; c4 < 32; ++c4) {
        uint32_t v = 0;
#pragma unroll
        for (int j = 0; j < 4; ++j) {
            float f = __builtin_nontemporal_load(xp + (size_t)(c4 * 4 + j) * PIX);
            v |= ((uint32_t)(uint8_t)(int8_t)((f > 0.f) - (f < 0.f))) << (8 * j);
        }
        tl[t * 33 + c4] = v;
    }
    __syncthreads();
    int pl = t >> 3, co = t & 7;
#pragma unroll
    for (int pass = 0; pass < 8; ++pass) {
        int p = pass * 32 + pl;
        int mg = blockIdx.x * 256 + p;
        int b2 = mg / PIX, hw2 = mg % PIX, h2 = hw2 / W, w2 = hw2 % W;
        size_t ob = ((size_t)(b2 * HP + h2 + 1) * WP + (w2 + 1)) * C + co * 16;
        v4i val;
#pragma unroll
        for (int k = 0; k < 4; ++k) val[k] = (int)tl[p * 33 + co * 4 + k];
        *(v4i*)(xs + ob) = val;
    }
}

// ---------------------------------------------------------------------------
// Binarize weights into MFMA B-fragment order, slot = r*6 + kh*3 + s, with
// o = (lane&15)*8 + n (lane-contiguous O). BN tables exactly numpy fp32.
__global__ __launch_bounds__(256) void prep_w(
    const float* __restrict__ w1, const float* __restrict__ w2,
    const float* __restrict__ g1, const float* __restrict__ be1,
    const float* __restrict__ mu1, const float* __restrict__ va1,
    const float* __restrict__ g2, const float* __restrict__ be2,
    const float* __restrict__ mu2, const float* __restrict__ va2,
    int8_t* __restrict__ wf1, int8_t* __restrict__ wf2,
    float* __restrict__ bnp) {
    int t = blockIdx.x * 256 + threadIdx.x;
    if (t < 256) {
        int o = t & 127;
        if (t < 128) {
            float inv = g1[o] / sqrtf(va1[o] + 1e-5f);
            bnp[o]       = inv;
            bnp[128 + o] = __fsub_rn(be1[o], __fmul_rn(mu1[o], inv));
        } else {
            float inv = g2[o] / sqrtf(va2[o] + 1e-5f);
            bnp[256 + o] = inv;
            bnp[384 + o] = __fsub_rn(be2[o], __fmul_rn(mu2[o], inv));
        }
    }
    if (t >= 2 * 18 * 8 * 64) return;
    int lane = t & 63;
    int nsub = (t >> 6) & 7;
    int kh   = (t >> 9) & 1;
    int tap  = (t >> 10) % 9;
    int which = (t >> 10) / 9;
    const float* w = which ? w2 : w1;
    int8_t* wf = which ? wf2 : wf1;
    int o = (lane & 15) * 8 + nsub;
    int cbase = kh * 64 + (lane >> 4) * 16;
    int r = tap / 3, s = tap % 3;
    int slot = r * 6 + kh * 3 + s;           // (r, kh, s) step order
    int8_t frag[16];
#pragma unroll
    for (int j = 0; j < 16; ++j) {
        float f = w[((size_t)(o * C + cbase + j) * 3 + r) * 3 + s];
        frag[j] = (int8_t)((f > 0.f) - (f < 0.f));
    }
    *(v4i*)(wf + (size_t)((slot * 8 + nsub) * 64 + lane) * 16) =
        *(const v4i*)frag;
}

// ---------------------------------------------------------------------------
// One tile's worth of conv for one wave: RG row-groups x 64 O (this block's
// half). Ping-pong 2x unrolled K-loop, no register copies.
// coff = ohalf*4: this block's channel offset within the l15*8 O-group.
template <int PHASE, int RG>
__device__ __forceinline__ void do_tile(
    int mwave, const int8_t* __restrict__ xs, const int8_t* wlds,
    const float* binv, const float* btt, int lane, int quad, int l15,
    int coff,
    const float* __restrict__ xres, int8_t* __restrict__ xs_next,
    float* __restrict__ out)
{
    int abase[RG];
#pragma unroll
    for (int rg = 0; rg < RG; ++rg) {
        int ma = mwave + rg * 16 + l15;
        int wa = ma % W; int ta = ma / W; int ha = ta % H; int ba = ta / H;
        abase[rg] = ((ba * HP + ha) * WP + wa) * C + quad * 16;
    }

    v4i acc[RG][4];
#pragma unroll
    for (int rg = 0; rg < RG; ++rg)
#pragma unroll
        for (int n = 0; n < 4; ++n) acc[rg][n] = (v4i)0;

    v4i a0[RG], a1[RG], bf0[4], bf1[4];
    // prologue: set0 <- step 0 (aoff = 0)
#pragma unroll
    for (int rg = 0; rg < RG; ++rg) a0[rg] = *(const v4i*)(xs + abase[rg]);
#pragma unroll
    for (int n = 0; n < 4; ++n)
        bf0[n] = *(const v4i*)(wlds + ((n * 64 + lane) << 4));

#pragma unroll 1   // keep rolled: full unroll hoists prefetches -> spills
    for (int s2 = 0; s2 < 18; s2 += 2) {
        // prefetch set1 <- step s2+1
        {
            int aoff = step_aoff(s2 + 1);
            const int8_t* lb = wlds + (s2 + 1) * 4096;
#pragma unroll
            for (int rg = 0; rg < RG; ++rg)
                a1[rg] = *(const v4i*)(xs + abase[rg] + aoff);
#pragma unroll
            for (int n = 0; n < 4; ++n)
                bf1[n] = *(const v4i*)(lb + ((n * 64 + lane) << 4));
        }
        // MFMA on set0 (loaded >= one half-step ago)
#pragma unroll
        for (int n = 0; n < 4; ++n)
#pragma unroll
            for (int rg = 0; rg < RG; ++rg)
                acc[rg][n] = __builtin_amdgcn_mfma_i32_16x16x64_i8(
                    a0[rg], bf0[n], acc[rg][n], 0, 0, 0);
        // prefetch set0 <- step s2+2
        if (s2 + 2 < 18) {
            int aoff = step_aoff(s2 + 2);
            const int8_t* lb = wlds + (s2 + 2) * 4096;
#pragma unroll
            for (int rg = 0; rg < RG; ++rg)
                a0[rg] = *(const v4i*)(xs + abase[rg] + aoff);
#pragma unroll
            for (int n = 0; n < 4; ++n)
                bf0[n] = *(const v4i*)(lb + ((n * 64 + lane) << 4));
        }
        // MFMA on set1
#pragma unroll
        for (int n = 0; n < 4; ++n)
#pragma unroll
            for (int rg = 0; rg < RG; ++rg)
                acc[rg][n] = __builtin_amdgcn_mfma_i32_16x16x64_i8(
                    a1[rg], bf1[n], acc[rg][n], 0, 0, 0);
    }

    // Epilogue. D layout: col = l15 (-> o = l15*8 + coff + n), row = quad*4+i.
#pragma unroll
    for (int rg = 0; rg < RG; ++rg) {
        int m0 = mwave + rg * 16 + quad * 4;         // multiple of 4; W%4==0
        int w0 = m0 % W; int t0 = m0 / W; int h0 = t0 % H; int b0 = t0 / H;
        if (PHASE == 1) {
            int base = ((b0 * HP + h0 + 1) * WP + (w0 + 1)) * C + l15 * 8 + coff;
#pragma unroll
            for (int i = 0; i < 4; ++i) {
                uint32_t wd = 0;
#pragma unroll
                for (int n = 0; n < 4; ++n) {
                    float y = __fadd_rn(__fmul_rn((float)acc[rg][n][i], binv[n]), btt[n]);
                    uint32_t sb = (uint8_t)(int8_t)((y > 0.f) - (y < 0.f));
                    wd |= sb << (8 * n);
                }
                *(uint32_t*)(xs_next + base + i * C) = wd;
            }
        } else {
            int pixb = b0 * C * PIX + h0 * W + w0;
#pragma unroll
            for (int n = 0; n < 4; ++n) {
                int idx = pixb + (l15 * 8 + coff + n) * PIX;
                v4f r = __builtin_nontemporal_load((const v4f*)(xres + idx));
                v4f z;
#pragma unroll
                for (int i = 0; i < 4; ++i) {
                    float y = __fadd_rn(__fmul_rn((float)acc[rg][n][i], binv[n]), btt[n]);
                    float v = __fadd_rn(y, r[i]);
                    z[i] = fminf(fmaxf(v, -1.f), 1.f);
                }
                __builtin_nontemporal_store(z, (v4f*)(out + idx));
            }
        }
    }
}

// ---------------------------------------------------------------------------
// Persistent binary conv. Grid = 512 blocks (2/CU: LDS 73,728 B/block),
// 512 thr = 8 waves (4 waves/SIMD total). Wave = 32 rows x 64 O (acc[2][4]).
// Block's O-half: ohalf = local&1 (pair blocks 8 bids apart -> same XCD ->
// shared xs reads + interleaved phase-1 stores merge in one L2).
// Schedule per XCD (xcd = bid&7, 64 blocks): 3 exact rounds over
// tiles [xcd*98, xcd*98+96) x {oh0,oh1}, then the 4 leftover tasks as 8
// half-tasks (RG=1, 16 rows/wave) on blocks local<8 -> wall 3.5 rounds.
template <int PHASE>
__global__ __launch_bounds__(512, 4) void conv_bin(
    const int8_t* __restrict__ xs,
    const int8_t* __restrict__ wf,
    const float* __restrict__ bnp,
    const float* __restrict__ xres,
    int8_t* __restrict__ xs_next,
    float* __restrict__ out)
{
    __shared__ int8_t wlds[18 * 4096];       // 73,728 B -> 2 blocks/CU
    int t = threadIdx.x, lane = t & 63, wv = t >> 6;
    int quad = lane >> 4, l15 = lane & 15;
    int xcd = blockIdx.x & 7, local = blockIdx.x >> 3;   // 64 blocks per XCD
    int ohalf = local & 1, coff = ohalf * 4;

    // one-time weight staging: this block's 4 nsub frags per slot.
    // wf v4i index (slot, nsub, lane) = slot*512 + nsub*64 + lane;
    // dest (slot, k, lane) = slot*256 + k*64 + lane, nsub = 4*ohalf + k.
    {
        const v4i* g = (const v4i*)wf;
        v4i* l = (v4i*)wlds;
        for (int i = t; i < 18 * 256; i += 512)
            l[i] = g[i + ((i >> 8) + ohalf) * 256];
    }
    float binv[4], btt[4];
    {
        int o0 = (PHASE == 1 ? 0 : 256) + l15 * 8 + coff;
#pragma unroll
        for (int n = 0; n < 4; ++n) { binv[n] = bnp[o0 + n]; btt[n] = bnp[o0 + 128 + n]; }
    }
    __syncthreads();

    int tbase = xcd * TPX + (local >> 1);
#pragma unroll 1
    for (int r = 0; r < 3; ++r)                          // exactly 3 rounds
        do_tile<PHASE, 2>((tbase + r * 32) * 256 + wv * 32, xs, wlds,
                          binv, btt, lane, quad, l15, coff,
                          xres, xs_next, out);
    if (local < 8) {                                     // tail: 4 tasks/XCD
        int tile = xcd * TPX + 96 + (local >> 2);
        int mw = tile * 256 + ((local >> 1) & 1) * 128 + wv * 16;
        do_tile<PHASE, 1>(mw, xs, wlds, binv, btt,
                          lane, quad, l15, coff, xres, xs_next, out);
    }
}

// ---------------------------------------------------------------------------
extern "C" void kernel_launch(void* const* d_in, const int* in_sizes, int n_in,
                              void* d_out, int out_size, void* d_ws, size_t ws_size,
                              hipStream_t stream) {
    const float* x   = (const float*)d_in[0];
    const float* w1  = (const float*)d_in[1];
    const float* w2  = (const float*)d_in[2];
    const float* g1  = (const float*)d_in[3];
    const float* be1 = (const float*)d_in[4];
    const float* mu1 = (const float*)d_in[5];
    const float* va1 = (const float*)d_in[6];
    const float* g2  = (const float*)d_in[7];
    const float* be2 = (const float*)d_in[8];
    const float* mu2 = (const float*)d_in[9];
    const float* va2 = (const float*)d_in[10];

    int8_t* ws  = (int8_t*)d_ws;
    int8_t* xs1 = ws + XS1_OFF;
    int8_t* xs2 = ws + XS2_OFF;
    int8_t* wf1 = ws + WF1_OFF;
    int8_t* wf2 = ws + WF2_OFF;
    float*  bnp = (float*)(ws + BNP_OFF);

    zero_halo<<<256, 256, 0, stream>>>(xs1, xs2);
    prep_x<<<M / 256, 256, 0, stream>>>(x, xs1);
    prep_w<<<(2 * 18 * 8 * 64 + 255) / 256, 256, 0, stream>>>(
        w1, w2, g1, be1, mu1, va1, g2, be2, mu2, va2, wf1, wf2, bnp);

    conv_bin<1><<<512, 512, 0, stream>>>(xs1, wf1, bnp, nullptr, xs2, nullptr);
    conv_bin<2><<<512, 512, 0, stream>>>(xs2, wf2, bnp, x, nullptr, (float*)d_out);
}

// Round 2
// 347.296 us; speedup vs baseline: 1.0283x; 1.0283x over previous
//
#include <hip/hip_runtime.h>
#include <cstdint>
#include <cstddef>

// Binarized basic block on MI355X.
// |acc| <= 9*128 = 1152 < THRESH=8000 -> the per-partial-sum clip never binds
// -> both convs are exact int convolutions of sign() values. int8 implicit
// GEMM via mfma_i32_16x16x64_i8; float ops bit-exact vs numpy fp32.
//
// R11 (on R9 base; R10's O-split REVERTED): DEPTH-2 SOFTWARE PIPELINE.
//  R10 lesson: doubling occupancy (2 blocks/CU) made it SLOWER (103->117us)
//  because per-wave prefetch->use slack halved; also 4B partial-line stores
//  amplified phase-1 HBM 4x (F89/W122 vs ideal 28/55). -> full-line stores
//  and 1 block/CU restored.
//  R9 residual: wall ~3900 cyc/K-step/CU vs pipe floors ~770 (MFMA 640,
//  LDS-B 768 overlap). Depth-1 ping-pong gives only ~160 cyc slack vs
//  ~500 cyc loaded latency -> all waves stall together.
//  -> 3-slot rotation, prefetch distance 2: A/B for step s+2 issued while
//     computing step s (~640 cyc slack). Regs ~200 (acc 64 + a 24 + bf 96),
//     still 2 waves/SIMD.

typedef int      v4i __attribute__((ext_vector_type(4)));
typedef float    v4f __attribute__((ext_vector_type(4)));
typedef unsigned int v2u __attribute__((ext_vector_type(2)));

constexpr int B = 64, C = 128, H = 56, W = 56;
constexpr int HP = H + 2, WP = W + 2;      // zero-padded spatial
constexpr int PIX = H * W;                 // 3136
constexpr int M = B * H * W;               // 200704 = 784 * 256
constexpr int NTILES = M / 256;            // 784 tiles of 256 rows
constexpr int TPX = NTILES / 8;            // 98 tiles per XCD

// workspace layout (bytes)
constexpr size_t XS_BYTES = (size_t)B * HP * WP * C;   // 27,557,888
constexpr size_t XS1_OFF = 0;
constexpr size_t XS2_OFF = XS_BYTES;
constexpr size_t WF_BYTES = 18 * 8192;                 // 147,456
constexpr size_t WF1_OFF = 2 * XS_BYTES;
constexpr size_t WF2_OFF = WF1_OFF + WF_BYTES;
constexpr size_t BNP_OFF = WF2_OFF + WF_BYTES;         // 4*128 floats

// step = r*6 + kh*3 + s  (r = step/6, kh = (step/3)&1, s = step%3)
// s-adjacent steps are distance-1 in x -> L1-resident window (R9).
__device__ __forceinline__ int step_aoff(int st) {
    int r = st / 6, kh = (st / 3) & 1, s = st % 3;
    return (r * WP + s) * C + kh * 64;
}

// ---------------------------------------------------------------------------
// Zero only the padded halos of xs1/xs2. 256 blocks: 4 per image.
__global__ __launch_bounds__(256) void zero_halo(int8_t* __restrict__ xs1,
                                                 int8_t* __restrict__ xs2) {
    int b = blockIdx.x >> 2;
    int q = blockIdx.x & 3;
    int t = q * 256 + threadIdx.x;           // 0..1023
    size_t ib = (size_t)b * HP * WP * C;
#pragma unroll
    for (int a = 0; a < 2; ++a) {
        uint32_t* p = (uint32_t*)((a ? xs2 : xs1) + ib);
        const int ROWD = WP * C / 4;             // 1856 dwords per padded row
        for (int i = t; i < ROWD; i += 1024) {
            p[i] = 0;
            p[(HP - 1) * ROWD + i] = 0;
        }
        for (int i = t; i < 56 * 2 * 32; i += 1024) {
            int r = i >> 6;
            int side = (i >> 5) & 1;
            int j = i & 31;
            p[((r + 1) * WP + side * (WP - 1)) * (C / 4) + j] = 0;
        }
    }
}

// ---------------------------------------------------------------------------
// sign(x) -> padded NHWC int8 via LDS transpose (16 B/lane full-line stores).
__global__ __launch_bounds__(256) void prep_x(const float* __restrict__ x,
                                              int8_t* __restrict__ xs) {
    __shared__ uint32_t tl[256 * 33];
    int t = threadIdx.x;
    int m = blockIdx.x * 256 + t;
    int b_ = m / PIX, hw = m % PIX;
    const float* xp = x + (size_t)b_ * C * PIX + hw;
#pragma unroll
    for (int c4 = 0; c4 < 32; ++c4) {
        uint32_t v = 0;
#pragma unroll
        for (int j = 0; j < 4; ++j) {
            float f = __builtin_nontemporal_load(xp + (size_t)(c4 * 4 + j) * PIX);
            v |= ((uint32_t)(uint8_t)(int8_t)((f > 0.f) - (f < 0.f))) << (8 * j);
        }
        tl[t * 33 + c4] = v;
    }
    __syncthreads();
    int pl = t >> 3, co = t & 7;
#pragma unroll
    for (int pass = 0; pass < 8; ++pass) {
        int p = pass * 32 + pl;
        int mg = blockIdx.x * 256 + p;
        int b2 = mg / PIX, hw2 = mg % PIX, h2 = hw2 / W, w2 = hw2 % W;
        size_t ob = ((size_t)(b2 * HP + h2 + 1) * WP + (w2 + 1)) * C + co * 16;
        v4i val;
#pragma unroll
        for (int k = 0; k < 4; ++k) val[k] = (int)tl[p * 33 + co * 4 + k];
        *(v4i*)(xs + ob) = val;
    }
}

// ---------------------------------------------------------------------------
// Binarize weights into MFMA B-fragment order, slot = r*6 + kh*3 + s, with
// o = (lane&15)*8 + n (lane-contiguous O). BN tables exactly numpy fp32.
__global__ __launch_bounds__(256) void prep_w(
    const float* __restrict__ w1, const float* __restrict__ w2,
    const float* __restrict__ g1, const float* __restrict__ be1,
    const float* __restrict__ mu1, const float* __restrict__ va1,
    const float* __restrict__ g2, const float* __restrict__ be2,
    const float* __restrict__ mu2, const float* __restrict__ va2,
    int8_t* __restrict__ wf1, int8_t* __restrict__ wf2,
    float* __restrict__ bnp) {
    int t = blockIdx.x * 256 + threadIdx.x;
    if (t < 256) {
        int o = t & 127;
        if (t < 128) {
            float inv = g1[o] / sqrtf(va1[o] + 1e-5f);
            bnp[o]       = inv;
            bnp[128 + o] = __fsub_rn(be1[o], __fmul_rn(mu1[o], inv));
        } else {
            float inv = g2[o] / sqrtf(va2[o] + 1e-5f);
            bnp[256 + o] = inv;
            bnp[384 + o] = __fsub_rn(be2[o], __fmul_rn(mu2[o], inv));
        }
    }
    if (t >= 2 * 18 * 8 * 64) return;
    int lane = t & 63;
    int nsub = (t >> 6) & 7;
    int kh   = (t >> 9) & 1;
    int tap  = (t >> 10) % 9;
    int which = (t >> 10) / 9;
    const float* w = which ? w2 : w1;
    int8_t* wf = which ? wf2 : wf1;
    int o = (lane & 15) * 8 + nsub;
    int cbase = kh * 64 + (lane >> 4) * 16;
    int r = tap / 3, s = tap % 3;
    int slot = r * 6 + kh * 3 + s;           // (r, kh, s) step order
    int8_t frag[16];
#pragma unroll
    for (int j = 0; j < 16; ++j) {
        float f = w[((size_t)(o * C + cbase + j) * 3 + r) * 3 + s];
        frag[j] = (int8_t)((f > 0.f) - (f < 0.f));
    }
    *(v4i*)(wf + (size_t)((slot * 8 + nsub) * 64 + lane) * 16) =
        *(const v4i*)frag;
}

// ---------------------------------------------------------------------------
// One tile's worth of conv for one wave: RG row-groups x all 128 O.
// Depth-2 pipeline: 3-slot rotation, prefetch step s+2 while computing s.
template <int PHASE, int RG>
__device__ __forceinline__ void do_tile(
    int mwave, const int8_t* __restrict__ xs, const int8_t* wlds,
    const float* binv, const float* btt, int lane, int quad, int l15,
    const float* __restrict__ xres, int8_t* __restrict__ xs_next,
    float* __restrict__ out)
{
    int abase[RG];
#pragma unroll
    for (int rg = 0; rg < RG; ++rg) {
        int ma = mwave + rg * 16 + l15;
        int wa = ma % W; int ta = ma / W; int ha = ta % H; int ba = ta / H;
        abase[rg] = ((ba * HP + ha) * WP + wa) * C + quad * 16;
    }

    v4i acc[RG][8];
#pragma unroll
    for (int rg = 0; rg < RG; ++rg)
#pragma unroll
        for (int n = 0; n < 8; ++n) acc[rg][n] = (v4i)0;

    // 3-slot rotating register file: slot = step % 3.
    v4i a[3][RG], bf[3][8];
    // prologue: slots 0,1 <- steps 0,1
#pragma unroll
    for (int sl = 0; sl < 2; ++sl) {
        int aoff = step_aoff(sl);
        const int8_t* lb = wlds + sl * 8192;
#pragma unroll
        for (int rg = 0; rg < RG; ++rg)
            a[sl][rg] = *(const v4i*)(xs + abase[rg] + aoff);
#pragma unroll
        for (int n = 0; n < 8; ++n)
            bf[sl][n] = *(const v4i*)(lb + ((n * 64 + lane) << 4));
    }

#pragma unroll 1   // keep rolled: full unroll hoists prefetches -> spills (R5)
    for (int it = 0; it < 6; ++it) {
#pragma unroll
        for (int k = 0; k < 3; ++k) {        // step st = it*3 + k, slot = k
            int st = it * 3 + k;
            int pf = st + 2;                 // prefetch target step
            if (pf < 18) {                   // slot (k+2)%3, free since st-1
                int aoff = step_aoff(pf);
                const int8_t* lb = wlds + pf * 8192;
#pragma unroll
                for (int rg = 0; rg < RG; ++rg)
                    a[(k + 2) % 3][rg] = *(const v4i*)(xs + abase[rg] + aoff);
#pragma unroll
                for (int n = 0; n < 8; ++n)
                    bf[(k + 2) % 3][n] =
                        *(const v4i*)(lb + ((n * 64 + lane) << 4));
            }
            // MFMA on slot k (its loads were issued 2 steps ago)
#pragma unroll
            for (int n = 0; n < 8; ++n)
#pragma unroll
                for (int rg = 0; rg < RG; ++rg)
                    acc[rg][n] = __builtin_amdgcn_mfma_i32_16x16x64_i8(
                        a[k][rg], bf[k][n], acc[rg][n], 0, 0, 0);
        }
    }

    // Epilogue. D layout: col = l15 (-> o = l15*8 + n), row = quad*4 + i.
#pragma unroll
    for (int rg = 0; rg < RG; ++rg) {
        int m0 = mwave + rg * 16 + quad * 4;         // multiple of 4; W%4==0
        int w0 = m0 % W; int t0 = m0 / W; int h0 = t0 % H; int b0 = t0 / H;
        if (PHASE == 1) {
            int base = ((b0 * HP + h0 + 1) * WP + (w0 + 1)) * C + l15 * 8;
#pragma unroll
            for (int i = 0; i < 4; ++i) {
                uint32_t lo = 0, hi = 0;
#pragma unroll
                for (int n = 0; n < 8; ++n) {
                    float y = __fadd_rn(__fmul_rn((float)acc[rg][n][i], binv[n]), btt[n]);
                    uint32_t sb = (uint8_t)(int8_t)((y > 0.f) - (y < 0.f));
                    if (n < 4) lo |= sb << (8 * n);
                    else       hi |= sb << (8 * (n - 4));
                }
                v2u pk; pk[0] = lo; pk[1] = hi;
                *(v2u*)(xs_next + base + i * C) = pk;
            }
        } else {
            int pixb = b0 * C * PIX + h0 * W + w0;
#pragma unroll
            for (int n = 0; n < 8; ++n) {
                int idx = pixb + (l15 * 8 + n) * PIX;
                v4f r = __builtin_nontemporal_load((const v4f*)(xres + idx));
                v4f z;
#pragma unroll
                for (int i = 0; i < 4; ++i) {
                    float y = __fadd_rn(__fmul_rn((float)acc[rg][n][i], binv[n]), btt[n]);
                    float v = __fadd_rn(y, r[i]);
                    z[i] = fminf(fmaxf(v, -1.f), 1.f);
                }
                __builtin_nontemporal_store(z, (v4f*)(out + idx));
            }
        }
    }
}

// ---------------------------------------------------------------------------
// Persistent binary conv. Grid = 256 blocks (1/CU, LDS-limited), 512 thr =
// 8 waves (2/SIMD). Wave = 32 rows x 128 O (acc[2][8]).
// Schedule per XCD (xcd = bid&7, 32 blocks): 3 exact rounds over tiles
// [xcd*98, xcd*98+96), then the 2 leftover tiles as 4 half-tiles (RG=1,
// 16 rows/wave) on blocks local<4 -> wall 3.5 rounds.
template <int PHASE>
__global__ __launch_bounds__(512, 1) void conv_bin(
    const int8_t* __restrict__ xs,
    const int8_t* __restrict__ wf,
    const float* __restrict__ bnp,
    const float* __restrict__ xres,
    int8_t* __restrict__ xs_next,
    float* __restrict__ out)
{
    __shared__ int8_t wlds[18 * 8192];       // 147,456 B
    int t = threadIdx.x, lane = t & 63, wv = t >> 6;
    int quad = lane >> 4, l15 = lane & 15;

    // one-time weight staging
    {
        const v4i* g = (const v4i*)wf;
        v4i* l = (v4i*)wlds;
        for (int i = t; i < 18 * 512; i += 512) l[i] = g[i];
    }
    float binv[8], btt[8];
    {
        int o0 = (PHASE == 1 ? 0 : 256) + l15 * 8;
        int o1 = (PHASE == 1 ? 128 : 384) + l15 * 8;
#pragma unroll
        for (int n = 0; n < 8; ++n) { binv[n] = bnp[o0 + n]; btt[n] = bnp[o1 + n]; }
    }
    __syncthreads();

    int xcd = blockIdx.x & 7, local = blockIdx.x >> 3;   // 32 blocks per XCD
#pragma unroll 1
    for (int tloc = local; tloc < 96; tloc += 32) {      // exactly 3 rounds
        int tile = xcd * TPX + tloc;
        do_tile<PHASE, 2>(tile * 256 + wv * 32, xs, wlds, binv, btt,
                          lane, quad, l15, xres, xs_next, out);
    }
    if (local < 4) {                                     // tail: 2 tiles/XCD
        int tile = xcd * TPX + 96 + (local >> 1);
        int mw = tile * 256 + (local & 1) * 128 + wv * 16;
        do_tile<PHASE, 1>(mw, xs, wlds, binv, btt,
                          lane, quad, l15, xres, xs_next, out);
    }
}

// ---------------------------------------------------------------------------
extern "C" void kernel_launch(void* const* d_in, const int* in_sizes, int n_in,
                              void* d_out, int out_size, void* d_ws, size_t ws_size,
                              hipStream_t stream) {
    const float* x   = (const float*)d_in[0];
    const float* w1  = (const float*)d_in[1];
    const float* w2  = (const float*)d_in[2];
    const float* g1  = (const float*)d_in[3];
    const float* be1 = (const float*)d_in[4];
    const float* mu1 = (const float*)d_in[5];
    const float* va1 = (const float*)d_in[6];
    const float* g2  = (const float*)d_in[7];
    const float* be2 = (const float*)d_in[8];
    const float* mu2 = (const float*)d_in[9];
    const float* va2 = (const float*)d_in[10];

    int8_t* ws  = (int8_t*)d_ws;
    int8_t* xs1 = ws + XS1_OFF;
    int8_t* xs2 = ws + XS2_OFF;
    int8_t* wf1 = ws + WF1_OFF;
    int8_t* wf2 = ws + WF2_OFF;
    float*  bnp = (float*)(ws + BNP_OFF);

    zero_halo<<<256, 256, 0, stream>>>(xs1, xs2);
    prep_x<<<M / 256, 256, 0, stream>>>(x, xs1);
    prep_w<<<(2 * 18 * 8 * 64 + 255) / 256, 256, 0, stream>>>(
        w1, w2, g1, be1, mu1, va1, g2, be2, mu2, va2, wf1, wf2, bnp);

    conv_bin<1><<<256, 512, 0, stream>>>(xs1, wf1, bnp, nullptr, xs2, nullptr);
    conv_bin<2><<<256, 512, 0, stream>>>(xs2, wf2, bnp, x, nullptr, (float*)d_out);
}

// Round 3
// 322.653 us; speedup vs baseline: 1.1069x; 1.0764x over previous
//
#include <hip/hip_runtime.h>
#include <cstdint>
#include <cstddef>

// Binarized basic block on MI355X.
// |acc| <= 9*128 = 1152 < THRESH=8000 -> the per-partial-sum clip never binds
// -> both convs are exact int convolutions of sign() values. int8 implicit
// GEMM via mfma_i32_16x16x64_i8; float ops bit-exact vs numpy fp32.
//
// R12 (on R9 base): FORCE the ping-pong pipeline with sched_barrier(0).
//  R9/R11 post-mortem: VGPR_Count 108/128 proves the compiler never kept the
//  prefetch sets live (needs 144/200) -> it sank all loads to just-before-use
//  and every step exposed full load latency (~500-900 cyc x 18 steps).
//  -> Pin the order per step: [prefetch set(s+1)] sched_barrier(0)
//     [setprio(1) 16xMFMA set(s) setprio(0)] sched_barrier(0).
//     Compiler must then emit counted waits (vmcnt(2)/lgkmcnt(8)) for the old
//     set while the new set's 10 loads fly under the MFMA block.
//  -> K-loop restructured r(rolled) x 6 unrolled (kh,s): all aoffs/slots are
//     compile-time (kills the st/6, st%3 magic-mul chains), set indices are
//     compile-time (no scratch).
//  Tell-tale: VGPR must rise to ~180-220. If it stays ~110, fences failed.

typedef int      v4i __attribute__((ext_vector_type(4)));
typedef float    v4f __attribute__((ext_vector_type(4)));
typedef unsigned int v2u __attribute__((ext_vector_type(2)));

constexpr int B = 64, C = 128, H = 56, W = 56;
constexpr int HP = H + 2, WP = W + 2;      // zero-padded spatial
constexpr int PIX = H * W;                 // 3136
constexpr int M = B * H * W;               // 200704 = 784 * 256
constexpr int NTILES = M / 256;            // 784 tiles of 256 rows
constexpr int TPX = NTILES / 8;            // 98 tiles per XCD

// workspace layout (bytes)
constexpr size_t XS_BYTES = (size_t)B * HP * WP * C;   // 27,557,888
constexpr size_t XS1_OFF = 0;
constexpr size_t XS2_OFF = XS_BYTES;
constexpr size_t WF_BYTES = 18 * 8192;                 // 147,456
constexpr size_t WF1_OFF = 2 * XS_BYTES;
constexpr size_t WF2_OFF = WF1_OFF + WF_BYTES;
constexpr size_t BNP_OFF = WF2_OFF + WF_BYTES;         // 4*128 floats

// ---------------------------------------------------------------------------
// Zero only the padded halos of xs1/xs2. 256 blocks: 4 per image.
__global__ __launch_bounds__(256) void zero_halo(int8_t* __restrict__ xs1,
                                                 int8_t* __restrict__ xs2) {
    int b = blockIdx.x >> 2;
    int q = blockIdx.x & 3;
    int t = q * 256 + threadIdx.x;           // 0..1023
    size_t ib = (size_t)b * HP * WP * C;
#pragma unroll
    for (int a = 0; a < 2; ++a) {
        uint32_t* p = (uint32_t*)((a ? xs2 : xs1) + ib);
        const int ROWD = WP * C / 4;             // 1856 dwords per padded row
        for (int i = t; i < ROWD; i += 1024) {
            p[i] = 0;
            p[(HP - 1) * ROWD + i] = 0;
        }
        for (int i = t; i < 56 * 2 * 32; i += 1024) {
            int r = i >> 6;
            int side = (i >> 5) & 1;
            int j = i & 31;
            p[((r + 1) * WP + side * (WP - 1)) * (C / 4) + j] = 0;
        }
    }
}

// ---------------------------------------------------------------------------
// sign(x) -> padded NHWC int8 via LDS transpose (16 B/lane full-line stores).
__global__ __launch_bounds__(256) void prep_x(const float* __restrict__ x,
                                              int8_t* __restrict__ xs) {
    __shared__ uint32_t tl[256 * 33];
    int t = threadIdx.x;
    int m = blockIdx.x * 256 + t;
    int b_ = m / PIX, hw = m % PIX;
    const float* xp = x + (size_t)b_ * C * PIX + hw;
#pragma unroll
    for (int c4 = 0; c4 < 32; ++c4) {
        uint32_t v = 0;
#pragma unroll
        for (int j = 0; j < 4; ++j) {
            float f = __builtin_nontemporal_load(xp + (size_t)(c4 * 4 + j) * PIX);
            v |= ((uint32_t)(uint8_t)(int8_t)((f > 0.f) - (f < 0.f))) << (8 * j);
        }
        tl[t * 33 + c4] = v;
    }
    __syncthreads();
    int pl = t >> 3, co = t & 7;
#pragma unroll
    for (int pass = 0; pass < 8; ++pass) {
        int p = pass * 32 + pl;
        int mg = blockIdx.x * 256 + p;
        int b2 = mg / PIX, hw2 = mg % PIX, h2 = hw2 / W, w2 = hw2 % W;
        size_t ob = ((size_t)(b2 * HP + h2 + 1) * WP + (w2 + 1)) * C + co * 16;
        v4i val;
#pragma unroll
        for (int k = 0; k < 4; ++k) val[k] = (int)tl[p * 33 + co * 4 + k];
        *(v4i*)(xs + ob) = val;
    }
}

// ---------------------------------------------------------------------------
// Binarize weights into MFMA B-fragment order, slot = r*6 + kh*3 + s, with
// o = (lane&15)*8 + n (lane-contiguous O). BN tables exactly numpy fp32.
__global__ __launch_bounds__(256) void prep_w(
    const float* __restrict__ w1, const float* __restrict__ w2,
    const float* __restrict__ g1, const float* __restrict__ be1,
    const float* __restrict__ mu1, const float* __restrict__ va1,
    const float* __restrict__ g2, const float* __restrict__ be2,
    const float* __restrict__ mu2, const float* __restrict__ va2,
    int8_t* __restrict__ wf1, int8_t* __restrict__ wf2,
    float* __restrict__ bnp) {
    int t = blockIdx.x * 256 + threadIdx.x;
    if (t < 256) {
        int o = t & 127;
        if (t < 128) {
            float inv = g1[o] / sqrtf(va1[o] + 1e-5f);
            bnp[o]       = inv;
            bnp[128 + o] = __fsub_rn(be1[o], __fmul_rn(mu1[o], inv));
        } else {
            float inv = g2[o] / sqrtf(va2[o] + 1e-5f);
            bnp[256 + o] = inv;
            bnp[384 + o] = __fsub_rn(be2[o], __fmul_rn(mu2[o], inv));
        }
    }
    if (t >= 2 * 18 * 8 * 64) return;
    int lane = t & 63;
    int nsub = (t >> 6) & 7;
    int kh   = (t >> 9) & 1;
    int tap  = (t >> 10) % 9;
    int which = (t >> 10) / 9;
    const float* w = which ? w2 : w1;
    int8_t* wf = which ? wf2 : wf1;
    int o = (lane & 15) * 8 + nsub;
    int cbase = kh * 64 + (lane >> 4) * 16;
    int r = tap / 3, s = tap % 3;
    int slot = r * 6 + kh * 3 + s;           // (r, kh, s) step order
    int8_t frag[16];
#pragma unroll
    for (int j = 0; j < 16; ++j) {
        float f = w[((size_t)(o * C + cbase + j) * 3 + r) * 3 + s];
        frag[j] = (int8_t)((f > 0.f) - (f < 0.f));
    }
    *(v4i*)(wf + (size_t)((slot * 8 + nsub) * 64 + lane) * 16) =
        *(const v4i*)frag;
}

// ---------------------------------------------------------------------------
// One tile's worth of conv for one wave: RG row-groups x all 128 O.
// Ping-pong pipeline PINNED with sched_barrier(0): prefetch(s+1) must be
// issued before MFMA(s); compiler emits counted waits for the old set only.
template <int PHASE, int RG>
__device__ __forceinline__ void do_tile(
    int mwave, const int8_t* __restrict__ xs, const int8_t* wlds,
    const float* binv, const float* btt, int lane, int quad, int l15,
    const float* __restrict__ xres, int8_t* __restrict__ xs_next,
    float* __restrict__ out)
{
    int abase[RG];
#pragma unroll
    for (int rg = 0; rg < RG; ++rg) {
        int ma = mwave + rg * 16 + l15;
        int wa = ma % W; int ta = ma / W; int ha = ta % H; int ba = ta / H;
        abase[rg] = ((ba * HP + ha) * WP + wa) * C + quad * 16;
    }
    int lidx = lane << 4;

    v4i acc[RG][8];
#pragma unroll
    for (int rg = 0; rg < RG; ++rg)
#pragma unroll
        for (int n = 0; n < 8; ++n) acc[rg][n] = (v4i)0;

    v4i a0[RG], a1[RG], bf0[8], bf1[8];
    // prologue: set0 <- step 0 (aoff = 0, slot 0)
#pragma unroll
    for (int rg = 0; rg < RG; ++rg) a0[rg] = *(const v4i*)(xs + abase[rg]);
#pragma unroll
    for (int n = 0; n < 8; ++n)
        bf0[n] = *(const v4i*)(wlds + n * 1024 + lidx);
    __builtin_amdgcn_sched_barrier(0);

    const int8_t* wl = wlds;                 // slot base for this r
    int aoffr = 0;                           // r * WP * C
#pragma unroll 1
    for (int r3 = 0; r3 < 3; ++r3) {
        // 6 fully-unrolled substeps kk = kh*3 + s; step st = r3*6 + kk.
#pragma unroll
        for (int kk = 0; kk < 6; ++kk) {
            const bool last = (r3 == 2) && (kk == 5);
            if (!last) {
                // prefetch step st+1 into the other set. Compile-time offsets:
                // kk<5: kh=(kk+1)/3, s=(kk+1)%3 of same r; kk==5: next r, kh=s=0.
                const int nkh = (kk + 1 < 6) ? ((kk + 1) / 3) : 0;
                const int ns  = (kk + 1 < 6) ? ((kk + 1) % 3) : 0;
                const int rbump = (kk + 1 < 6) ? 0 : WP * C;
                int naoff = aoffr + rbump + nkh * 64 + ns * C;
                const int8_t* lb = wl + (kk + 1) * 8192;   // slot st+1
                if (((kk + 1) & 1) == 0) {
#pragma unroll
                    for (int rg = 0; rg < RG; ++rg)
                        a0[rg] = *(const v4i*)(xs + abase[rg] + naoff);
#pragma unroll
                    for (int n = 0; n < 8; ++n)
                        bf0[n] = *(const v4i*)(lb + n * 1024 + lidx);
                } else {
#pragma unroll
                    for (int rg = 0; rg < RG; ++rg)
                        a1[rg] = *(const v4i*)(xs + abase[rg] + naoff);
#pragma unroll
                    for (int n = 0; n < 8; ++n)
                        bf1[n] = *(const v4i*)(lb + n * 1024 + lidx);
                }
            }
            // Fence: loads above may not sink below; MFMAs may not hoist above.
            __builtin_amdgcn_sched_barrier(0);
            __builtin_amdgcn_s_setprio(1);
            if ((kk & 1) == 0) {
#pragma unroll
                for (int n = 0; n < 8; ++n)
#pragma unroll
                    for (int rg = 0; rg < RG; ++rg)
                        acc[rg][n] = __builtin_amdgcn_mfma_i32_16x16x64_i8(
                            a0[rg], bf0[n], acc[rg][n], 0, 0, 0);
            } else {
#pragma unroll
                for (int n = 0; n < 8; ++n)
#pragma unroll
                    for (int rg = 0; rg < RG; ++rg)
                        acc[rg][n] = __builtin_amdgcn_mfma_i32_16x16x64_i8(
                            a1[rg], bf1[n], acc[rg][n], 0, 0, 0);
            }
            __builtin_amdgcn_s_setprio(0);
            __builtin_amdgcn_sched_barrier(0);
        }
        aoffr += WP * C;
        wl += 6 * 8192;
    }

    // Epilogue. D layout: col = l15 (-> o = l15*8 + n), row = quad*4 + i.
#pragma unroll
    for (int rg = 0; rg < RG; ++rg) {
        int m0 = mwave + rg * 16 + quad * 4;         // multiple of 4; W%4==0
        int w0 = m0 % W; int t0 = m0 / W; int h0 = t0 % H; int b0 = t0 / H;
        if (PHASE == 1) {
            int base = ((b0 * HP + h0 + 1) * WP + (w0 + 1)) * C + l15 * 8;
#pragma unroll
            for (int i = 0; i < 4; ++i) {
                uint32_t lo = 0, hi = 0;
#pragma unroll
                for (int n = 0; n < 8; ++n) {
                    float y = __fadd_rn(__fmul_rn((float)acc[rg][n][i], binv[n]), btt[n]);
                    uint32_t sb = (uint8_t)(int8_t)((y > 0.f) - (y < 0.f));
                    if (n < 4) lo |= sb << (8 * n);
                    else       hi |= sb << (8 * (n - 4));
                }
                v2u pk; pk[0] = lo; pk[1] = hi;
                *(v2u*)(xs_next + base + i * C) = pk;
            }
        } else {
            int pixb = b0 * C * PIX + h0 * W + w0;
#pragma unroll
            for (int n = 0; n < 8; ++n) {
                int idx = pixb + (l15 * 8 + n) * PIX;
                v4f r = __builtin_nontemporal_load((const v4f*)(xres + idx));
                v4f z;
#pragma unroll
                for (int i = 0; i < 4; ++i) {
                    float y = __fadd_rn(__fmul_rn((float)acc[rg][n][i], binv[n]), btt[n]);
                    float v = __fadd_rn(y, r[i]);
                    z[i] = fminf(fmaxf(v, -1.f), 1.f);
                }
                __builtin_nontemporal_store(z, (v4f*)(out + idx));
            }
        }
    }
}

// ---------------------------------------------------------------------------
// Persistent binary conv. Grid = 256 blocks (1/CU, LDS-limited), 512 thr =
// 8 waves (2/SIMD). Wave = 32 rows x 128 O (acc[2][8]).
// Schedule per XCD (xcd = bid&7, 32 blocks): 3 exact rounds over tiles
// [xcd*98, xcd*98+96), then the 2 leftover tiles as 4 half-tiles (RG=1,
// 16 rows/wave) on blocks local<4 -> wall 3.5 rounds.
template <int PHASE>
__global__ __launch_bounds__(512, 1) void conv_bin(
    const int8_t* __restrict__ xs,
    const int8_t* __restrict__ wf,
    const float* __restrict__ bnp,
    const float* __restrict__ xres,
    int8_t* __restrict__ xs_next,
    float* __restrict__ out)
{
    __shared__ int8_t wlds[18 * 8192];       // 147,456 B
    int t = threadIdx.x, lane = t & 63, wv = t >> 6;
    int quad = lane >> 4, l15 = lane & 15;

    // one-time weight staging
    {
        const v4i* g = (const v4i*)wf;
        v4i* l = (v4i*)wlds;
        for (int i = t; i < 18 * 512; i += 512) l[i] = g[i];
    }
    float binv[8], btt[8];
    {
        int o0 = (PHASE == 1 ? 0 : 256) + l15 * 8;
        int o1 = (PHASE == 1 ? 128 : 384) + l15 * 8;
#pragma unroll
        for (int n = 0; n < 8; ++n) { binv[n] = bnp[o0 + n]; btt[n] = bnp[o1 + n]; }
    }
    __syncthreads();

    int xcd = blockIdx.x & 7, local = blockIdx.x >> 3;   // 32 blocks per XCD
#pragma unroll 1
    for (int tloc = local; tloc < 96; tloc += 32) {      // exactly 3 rounds
        int tile = xcd * TPX + tloc;
        do_tile<PHASE, 2>(tile * 256 + wv * 32, xs, wlds, binv, btt,
                          lane, quad, l15, xres, xs_next, out);
    }
    if (local < 4) {                                     // tail: 2 tiles/XCD
        int tile = xcd * TPX + 96 + (local >> 1);
        int mw = tile * 256 + (local & 1) * 128 + wv * 16;
        do_tile<PHASE, 1>(mw, xs, wlds, binv, btt,
                          lane, quad, l15, xres, xs_next, out);
    }
}

// ---------------------------------------------------------------------------
extern "C" void kernel_launch(void* const* d_in, const int* in_sizes, int n_in,
                              void* d_out, int out_size, void* d_ws, size_t ws_size,
                              hipStream_t stream) {
    const float* x   = (const float*)d_in[0];
    const float* w1  = (const float*)d_in[1];
    const float* w2  = (const float*)d_in[2];
    const float* g1  = (const float*)d_in[3];
    const float* be1 = (const float*)d_in[4];
    const float* mu1 = (const float*)d_in[5];
    const float* va1 = (const float*)d_in[6];
    const float* g2  = (const float*)d_in[7];
    const float* be2 = (const float*)d_in[8];
    const float* mu2 = (const float*)d_in[9];
    const float* va2 = (const float*)d_in[10];

    int8_t* ws  = (int8_t*)d_ws;
    int8_t* xs1 = ws + XS1_OFF;
    int8_t* xs2 = ws + XS2_OFF;
    int8_t* wf1 = ws + WF1_OFF;
    int8_t* wf2 = ws + WF2_OFF;
    float*  bnp = (float*)(ws + BNP_OFF);

    zero_halo<<<256, 256, 0, stream>>>(xs1, xs2);
    prep_x<<<M / 256, 256, 0, stream>>>(x, xs1);
    prep_w<<<(2 * 18 * 8 * 64 + 255) / 256, 256, 0, stream>>>(
        w1, w2, g1, be1, mu1, va1, g2, be2, mu2, va2, wf1, wf2, bnp);

    conv_bin<1><<<256, 512, 0, stream>>>(xs1, wf1, bnp, nullptr, xs2, nullptr);
    conv_bin<2><<<256, 512, 0, stream>>>(xs2, wf2, bnp, x, nullptr, (float*)d_out);
}